// Round 5
// baseline (177.543 us; speedup 1.0000x reference)
//
#include <hip/hip_runtime.h>
#include <stdint.h>
#include <math.h>

// ============================================================================
// SliceKernel — exact JAX threefry slice sampler, single fused kernel.
// R5: (1) W moved out of LDS into a packed, coalesced global layout in d_ws
//     (LDS 132->34 KiB => 3-4 blocks/CU instead of 1), 512-thread blocks.
// (2) eps guard tightened 3.5x (4e-4+8e-5|u|+8e-6u^2): still >=4x the
//     worst-case chain-vs-quadratic rounding discrepancy.
// VALUE-PATH ARITHMETIC FROZEN (R1-R4, absmax 0.05078125):
//   dirs: u01 -> um -> sqrt2*erfinv -> /nrm; partial j, m-ascending; tree
//         pairing j^8,j^4,j^2,j^1 (shfl_xor 32,16,8,4 with j=lane>>2)
//   pot:  per-row k-ascending FMA chain; partials m-ascending; same tree
//   sampler: b-schedule, u updates, x+u*d exactly as reference
// Decisions: f64 quadratic ps(u)=pot0-u g-u^2 h/2, eps guard, bit-exact
// chain fallback on near-ties (R3/R4: 0 flips).
// Wpack layout: element (m,q,j,e) at ((q*8+m)*16+j)*4+e  -> per (q,m) the 16
// lanes j=0..15 read one contiguous 256B block (4-way lane duplication).
// ============================================================================

#define BD 128   // feature dim D
#define NB 65536 // chains B
#define WS 132   // padded LDS row stride (floats)
#define CPB 32   // chains per block
#define TPB 512  // threads per block

// ---------------- threefry2x32 (host + device) ------------------------------
__host__ __device__ inline uint32_t rotl32(uint32_t v, int s) {
  return (v << s) | (v >> (32 - s));
}

__host__ __device__ inline void tf2x32(uint32_t k0, uint32_t k1,
                                       uint32_t c0, uint32_t c1,
                                       uint32_t* o0, uint32_t* o1) {
  uint32_t ks2 = k0 ^ k1 ^ 0x1BD11BDAu;
  uint32_t x0 = c0 + k0, x1 = c1 + k1;
#define TFR(r) x0 += x1; x1 = rotl32(x1, (r)); x1 ^= x0;
  TFR(13) TFR(15) TFR(26) TFR(6)
  x0 += k1;  x1 += ks2 + 1u;
  TFR(17) TFR(29) TFR(16) TFR(24)
  x0 += ks2; x1 += k0 + 2u;
  TFR(13) TFR(15) TFR(26) TFR(6)
  x0 += k0;  x1 += k1 + 3u;
  TFR(17) TFR(29) TFR(16) TFR(24)
  x0 += k1;  x1 += ks2 + 4u;
  TFR(13) TFR(15) TFR(26) TFR(6)
  x0 += ks2; x1 += k0 + 5u;
#undef TFR
  *o0 = x0; *o1 = x1;
}

__device__ inline uint32_t jbits(uint32_t k0, uint32_t k1, uint32_t n) {
  uint32_t a, b;
  tf2x32(k0, k1, 0u, n, &a, &b);
  return a ^ b;
}

// ---------------- XLA-exact scalar math -------------------------------------
__device__ inline float u01(uint32_t bits) {
  return __fsub_rn(__uint_as_float((bits >> 9) | 0x3f800000u), 1.0f);
}

__device__ inline float xla_log1p(float x) {
  float u  = __fadd_rn(x, 1.0f);
  float lg = (float)log((double)u);
  float sm = __fmul_rn(__fadd_rn(__fmul_rn(-0.5f, x), 1.0f), x);
  return (fabsf(x) < 1e-4f) ? sm : lg;
}

__device__ inline float xla_erfinv(float x) {
  float xx = __fmul_rn(x, x);
  float w  = -xla_log1p(-xx);
  float p;
  if (w < 5.0f) {
    float ww = __fsub_rn(w, 2.5f);
    p = 2.81022636e-08f;
    p = __fadd_rn(3.43273939e-07f,  __fmul_rn(p, ww));
    p = __fadd_rn(-3.5233877e-06f,  __fmul_rn(p, ww));
    p = __fadd_rn(-4.39150654e-06f, __fmul_rn(p, ww));
    p = __fadd_rn(0.00021858087f,   __fmul_rn(p, ww));
    p = __fadd_rn(-0.00125372503f,  __fmul_rn(p, ww));
    p = __fadd_rn(-0.00417768164f,  __fmul_rn(p, ww));
    p = __fadd_rn(0.246640727f,     __fmul_rn(p, ww));
    p = __fadd_rn(1.50140941f,      __fmul_rn(p, ww));
  } else {
    float ww = __fsub_rn(__fsqrt_rn(w), 3.0f);
    p = -0.000200214257f;
    p = __fadd_rn(0.000100950558f,  __fmul_rn(p, ww));
    p = __fadd_rn(0.00134934322f,   __fmul_rn(p, ww));
    p = __fadd_rn(-0.00367342844f,  __fmul_rn(p, ww));
    p = __fadd_rn(0.00573950773f,   __fmul_rn(p, ww));
    p = __fadd_rn(-0.0076224613f,   __fmul_rn(p, ww));
    p = __fadd_rn(0.00943887047f,   __fmul_rn(p, ww));
    p = __fadd_rn(1.00167406f,      __fmul_rn(p, ww));
    p = __fadd_rn(2.83297682f,      __fmul_rn(p, ww));
  }
  return __fmul_rn(p, x);
}

// ---------------- W pack kernel ---------------------------------------------
// Wp[((q*8+m)*16+j)*4+e] = W[(16m+j)*128 + q*4 + e]
__global__ __launch_bounds__(1024) void pack_w_kernel(
    const float* __restrict__ Wg, float* __restrict__ Wp) {
  int i = blockIdx.x * 1024 + threadIdx.x;  // 0..16383
  int e = i & 3, j = (i >> 2) & 15, m = (i >> 6) & 7, q = i >> 9;
  Wp[i] = Wg[(16 * m + j) * 128 + q * 4 + e];
}

// ---------------- bit-exact chain potential (fallback path) -----------------
template <bool PACKED>
__device__ __attribute__((always_inline)) inline float potential16(
    const float* __restrict__ xr, const float* __restrict__ dr,
    const float* __restrict__ Wsrc, int j, float coef) {
  float z[8] = {0.f, 0.f, 0.f, 0.f, 0.f, 0.f, 0.f, 0.f};
#pragma unroll 2
  for (int q = 0; q < 32; ++q) {
    float4 xv = *(const float4*)(xr + q * 4);
    float4 dv = *(const float4*)(dr + q * 4);
    float c0 = __fadd_rn(xv.x, __fmul_rn(coef, dv.x));
    float c1 = __fadd_rn(xv.y, __fmul_rn(coef, dv.y));
    float c2 = __fadd_rn(xv.z, __fmul_rn(coef, dv.z));
    float c3 = __fadd_rn(xv.w, __fmul_rn(coef, dv.w));
#pragma unroll
    for (int m = 0; m < 8; ++m) {
      const float* wa = PACKED ? (Wsrc + (((q * 8 + m) * 16 + j) << 2))
                               : (Wsrc + (16 * m + j) * 128 + q * 4);
      float4 wv = *(const float4*)wa;
      z[m] = __fmaf_rn(c0, wv.x, z[m]);
      z[m] = __fmaf_rn(c1, wv.y, z[m]);
      z[m] = __fmaf_rn(c2, wv.z, z[m]);
      z[m] = __fmaf_rn(c3, wv.w, z[m]);
    }
  }
  float pr = 0.0f;
#pragma unroll
  for (int m = 0; m < 8; ++m) pr = __fadd_rn(pr, __fmul_rn(z[m], z[m]));
#pragma unroll
  for (int msk = 32; msk >= 4; msk >>= 1)
    pr = __fadd_rn(pr, __shfl_xor(pr, msk));
  return __fmul_rn(-0.5f, pr);
}

// certainty margin: >=4x worst-case chain-vs-quadratic rounding discrepancy
__device__ inline double epsb(float u) {
  double au = fabs((double)u);
  return 4e-4 + 8e-5 * au + 8e-6 * au * au;
}

// ---------------- the fused kernel ------------------------------------------
struct KeyArgs {
  uint32_t ky0, ky1;   // k_y
  uint32_t ku0, ku1;   // k_u0
  uint32_t kd0, kd1;   // k_dir
  uint32_t ks[48];     // 24 shrink keys
};

template <bool PACKED>
__global__ __launch_bounds__(TPB, 6) void slice_fused_kernel(
    const float* __restrict__ X, const float* __restrict__ Wsrc,
    float* __restrict__ OUT, KeyArgs ka) {
  __shared__ __align__(16) float Xl[CPB * WS];  // 16,896 B
  __shared__ __align__(16) float Dl[CPB * WS];  // 16,896 B  (33.8 KiB total)

  const int tid   = threadIdx.x;
  const int cbase = blockIdx.x * CPB;

  // ---- stage X ----
  for (int i = tid; i < CPB * 32; i += TPB) {
    int c = i >> 5, q = i & 31;
    *(float4*)&Xl[c * WS + q * 4] = ((const float4*)(X + (size_t)(cbase + c) * BD))[q];
  }

  const int wave = tid >> 6, lane = tid & 63;
  const int c    = lane & 3;          // chain-in-wave
  const int j    = lane >> 2;         // partial index 0..15 (rows 16m+j)
  const int cl   = wave * 4 + c;      // chain local (0..31)
  const uint32_t chain = (uint32_t)(cbase + cl);

  // ---- dirs phase (registers; overlaps X staging latency) ----
  {
    const float LO    = __uint_as_float(0xBF7FFFFFu);
    const float SQRT2 = __uint_as_float(0x3FB504F3u);
    float vm[8];
#pragma unroll
    for (int m = 0; m < 8; ++m) {
      uint32_t n = chain * 128u + (uint32_t)(16 * m + j);
      float f  = u01(jbits(ka.kd0, ka.kd1, n));
      float um = fmaxf(LO, __fadd_rn(__fmul_rn(f, 2.0f), LO));
      vm[m] = __fmul_rn(SQRT2, xla_erfinv(um));
    }
    float pr = 0.0f;
#pragma unroll
    for (int m = 0; m < 8; ++m) pr = __fadd_rn(pr, __fmul_rn(vm[m], vm[m]));
#pragma unroll
    for (int msk = 32; msk >= 4; msk >>= 1)
      pr = __fadd_rn(pr, __shfl_xor(pr, msk));
    float nrm = __fsqrt_rn(pr);
#pragma unroll
    for (int m = 0; m < 8; ++m)
      Dl[cl * WS + 16 * m + j] = vm[m] / nrm;
  }

  __syncthreads();  // single block barrier

  const float* xr = &Xl[cl * WS];
  const float* dr = &Dl[cl * WS];

  // ---- fused matvec: za = W x (chain-exact), zb = W d (surrogate only) ----
  float za[8], zb[8];
#pragma unroll
  for (int m = 0; m < 8; ++m) { za[m] = 0.0f; zb[m] = 0.0f; }
#pragma unroll 2
  for (int q = 0; q < 32; ++q) {
    float4 xv = *(const float4*)(xr + q * 4);
    float4 dv = *(const float4*)(dr + q * 4);
#pragma unroll
    for (int m = 0; m < 8; ++m) {
      const float* wa = PACKED ? (Wsrc + (((q * 8 + m) * 16 + j) << 2))
                               : (Wsrc + (16 * m + j) * 128 + q * 4);
      float4 wv = *(const float4*)wa;
      za[m] = __fmaf_rn(xv.x, wv.x, za[m]);
      za[m] = __fmaf_rn(xv.y, wv.y, za[m]);
      za[m] = __fmaf_rn(xv.z, wv.z, za[m]);
      za[m] = __fmaf_rn(xv.w, wv.w, za[m]);
      zb[m] = __fmaf_rn(dv.x, wv.x, zb[m]);
      zb[m] = __fmaf_rn(dv.y, wv.y, zb[m]);
      zb[m] = __fmaf_rn(dv.z, wv.z, zb[m]);
      zb[m] = __fmaf_rn(dv.w, wv.w, zb[m]);
    }
  }

  // pot0: chain-exact f32 reduce
  float pr0 = 0.0f;
#pragma unroll
  for (int m = 0; m < 8; ++m) pr0 = __fadd_rn(pr0, __fmul_rn(za[m], za[m]));
#pragma unroll
  for (int msk = 32; msk >= 4; msk >>= 1)
    pr0 = __fadd_rn(pr0, __shfl_xor(pr0, msk));
  float pot0 = __fmul_rn(-0.5f, pr0);

  // g = a·b, h = ‖b‖² in f64 (surrogate only)
  double gl = 0.0, hl = 0.0;
#pragma unroll
  for (int m = 0; m < 8; ++m) {
    gl += (double)za[m] * (double)zb[m];
    hl += (double)zb[m] * (double)zb[m];
  }
#pragma unroll
  for (int msk = 32; msk >= 4; msk >>= 1) {
    gl += __shfl_xor(gl, msk);
    hl += __shfl_xor(hl, msk);
  }
  const double g = gl, h = hl;
  const double potd0 = (double)pot0;

  // ---- y = log1p(-U) + pot0 ----
  float Uy = u01(jbits(ka.ky0, ka.ky1, chain));
  float y  = __fadd_rn(xla_log1p(-Uy), pot0);
  const double yd = (double)y;
  bool mask0 = (y < pot0);

  // ---- bracket expansion ----
  float lb = 0.0f, ub = 0.0f;
#pragma unroll 1
  for (int side = 0; side < 2; ++side) {
    bool m = mask0;
    float b = 0.0f, pw = 1.0f;
#pragma unroll 1
    for (int i = 0; i < 16; ++i) {
      if (!__any((int)m)) break;
      float step = __fmul_rn(0.1f, pw);
      pw = __fmul_rn(pw, 1.5f);
      if (m) b = side ? __fadd_rn(b, step) : __fsub_rn(b, step);
      double bd   = (double)b;
      double diff = (potd0 - bd * g - 0.5 * bd * bd * h) - yd;
      bool need = m && (fabs(diff) <= epsb(b));
      float pe = 0.0f;
      if (__any((int)need)) pe = potential16<PACKED>(xr, dr, Wsrc, j, b);
      bool cont = need ? (y < pe) : (diff > 0.0);
      m = m && cont;
    }
    if (side == 0) lb = b; else ub = b;
  }

  // ---- initial proposal ----
  float U0 = u01(jbits(ka.ku0, ka.ku1, chain));
  float u  = __fadd_rn(__fmul_rn(U0, __fsub_rn(ub, lb)), lb);
  bool rej;
  {
    double ud   = (double)u;
    double diff = (potd0 - ud * g - 0.5 * ud * ud * h) - yd;
    bool need = fabs(diff) <= epsb(u);
    float pe = 0.0f;
    if (__any((int)need)) pe = potential16<PACKED>(xr, dr, Wsrc, j, u);
    rej = need ? (pe < y) : (diff < 0.0);
  }

  // ---- shrinkage ----
#pragma unroll 1
  for (int t = 0; t < 24; ++t) {
    if (!__any((int)rej)) break;
    if (rej) {
      if (u < 0.0f) lb = u; else ub = u;
      float Ut = u01(jbits(ka.ks[2 * t], ka.ks[2 * t + 1], chain));
      u = __fadd_rn(__fmul_rn(Ut, __fsub_rn(ub, lb)), lb);
    }
    double ud   = (double)u;
    double diff = (potd0 - ud * g - 0.5 * ud * ud * h) - yd;
    bool need = rej && (fabs(diff) <= epsb(u));
    float pe = 0.0f;
    if (__any((int)need)) pe = potential16<PACKED>(xr, dr, Wsrc, j, u);
    bool rj = need ? (pe < y) : (diff < 0.0);
    rej = rej && rj;
  }

  // ---- x_new = x + u*dirs (exact); lane (c,j) writes quads 2j, 2j+1 ----
  float* orow = OUT + (size_t)chain * BD;
#pragma unroll
  for (int hh = 0; hh < 2; ++hh) {
    int q = j * 2 + hh;
    float4 xv = *(const float4*)(xr + q * 4);
    float4 dv = *(const float4*)(dr + q * 4);
    float4 o;
    o.x = __fadd_rn(xv.x, __fmul_rn(u, dv.x));
    o.y = __fadd_rn(xv.y, __fmul_rn(u, dv.y));
    o.z = __fadd_rn(xv.z, __fmul_rn(u, dv.z));
    o.w = __fadd_rn(xv.w, __fmul_rn(u, dv.w));
    *(float4*)&orow[q * 4] = o;
  }
}

// ---------------- launcher ---------------------------------------------------
extern "C" void kernel_launch(void* const* d_in, const int* in_sizes, int n_in,
                              void* d_out, int out_size, void* d_ws, size_t ws_size,
                              hipStream_t stream) {
  (void)in_sizes; (void)n_in; (void)out_size;
  const float* x = (const float*)d_in[0];
  const float* W = (const float*)d_in[1];
  float* out = (float*)d_out;

  const uint32_t R0 = 0u, R1 = 42u;  // jax.random.key(42)
  uint32_t ky0, ky1, kd0, kd1, ku0, ku1, ksh0, ksh1;
  tf2x32(R0, R1, 0u, 0u, &ky0, &ky1);
  tf2x32(R0, R1, 0u, 1u, &kd0, &kd1);
  tf2x32(R0, R1, 0u, 2u, &ku0, &ku1);
  tf2x32(R0, R1, 0u, 3u, &ksh0, &ksh1);

  KeyArgs ka;
  ka.ky0 = ky0; ka.ky1 = ky1; ka.ku0 = ku0; ka.ku1 = ku1;
  ka.kd0 = kd0; ka.kd1 = kd1;
  for (uint32_t t = 0; t < 24; ++t) {
    uint32_t a, b;
    tf2x32(ksh0, ksh1, 0u, t, &a, &b);
    ka.ks[2 * t] = a; ka.ks[2 * t + 1] = b;
  }

  const bool packed = (ws_size >= (size_t)(BD * BD * sizeof(float)));
  if (packed) {
    pack_w_kernel<<<dim3(16), dim3(1024), 0, stream>>>(W, (float*)d_ws);
    slice_fused_kernel<true><<<dim3(NB / CPB), dim3(TPB), 0, stream>>>(
        x, (const float*)d_ws, out, ka);
  } else {
    slice_fused_kernel<false><<<dim3(NB / CPB), dim3(TPB), 0, stream>>>(
        x, W, out, ka);
  }
}

// Round 6
// 150.895 us; speedup vs baseline: 1.1766x; 1.1766x over previous
//
#include <hip/hip_runtime.h>
#include <stdint.h>
#include <math.h>

// ============================================================================
// SliceKernel — exact JAX threefry slice sampler, single fused kernel.
// R6 = R4 structure EXACTLY (W in LDS: its broadcast reads beat global, R5
// proved the global-W path regresses) + eps guard tightened 3.75x:
//   eps = 4e-4 + 8e-5|u| + 8e-6 u^2   (>=3x worst-case chain-vs-f64-quadratic
//   rounding discrepancy ~1.2e-4*(1+|u|) at |pot|~64, D=128 f32 chain)
// R4 budget analysis: fallback potential16 calls were ~2.5/wave = ~half of
// all VALU cycles; shrink iterates converge onto |pot-y|~0 so the old band
// (1.5e-3) caught them structurally. Tighter band -> ~0.7 calls/wave.
// VALUE-PATH ARITHMETIC FROZEN (R1-R5, absmax 0.05078125):
//   dirs: u01 -> um -> sqrt2*erfinv -> /nrm; partial j, m-ascending; tree
//         pairing j^8,j^4,j^2,j^1 (shfl_xor 32,16,8,4 with j=lane>>2)
//   pot:  per-row k-ascending FMA chain; partials m-ascending; same tree
//   sampler: b-schedule, u updates, x+u*d exactly as reference
// Decisions: f64 quadratic ps(u)=pot0-u g-u^2 h/2, eps guard, bit-exact
// chain fallback on near-ties (R3/R4: 0 flips at 0.05078125).
// ============================================================================

#define BD 128   // feature dim D
#define NB 65536 // chains B
#define WS 132   // padded LDS row stride (floats)

// ---------------- threefry2x32 (host + device) ------------------------------
__host__ __device__ inline uint32_t rotl32(uint32_t v, int s) {
  return (v << s) | (v >> (32 - s));
}

__host__ __device__ inline void tf2x32(uint32_t k0, uint32_t k1,
                                       uint32_t c0, uint32_t c1,
                                       uint32_t* o0, uint32_t* o1) {
  uint32_t ks2 = k0 ^ k1 ^ 0x1BD11BDAu;
  uint32_t x0 = c0 + k0, x1 = c1 + k1;
#define TFR(r) x0 += x1; x1 = rotl32(x1, (r)); x1 ^= x0;
  TFR(13) TFR(15) TFR(26) TFR(6)
  x0 += k1;  x1 += ks2 + 1u;
  TFR(17) TFR(29) TFR(16) TFR(24)
  x0 += ks2; x1 += k0 + 2u;
  TFR(13) TFR(15) TFR(26) TFR(6)
  x0 += k0;  x1 += k1 + 3u;
  TFR(17) TFR(29) TFR(16) TFR(24)
  x0 += k1;  x1 += ks2 + 4u;
  TFR(13) TFR(15) TFR(26) TFR(6)
  x0 += ks2; x1 += k0 + 5u;
#undef TFR
  *o0 = x0; *o1 = x1;
}

__device__ inline uint32_t jbits(uint32_t k0, uint32_t k1, uint32_t n) {
  uint32_t a, b;
  tf2x32(k0, k1, 0u, n, &a, &b);
  return a ^ b;
}

// ---------------- XLA-exact scalar math -------------------------------------
__device__ inline float u01(uint32_t bits) {
  return __fsub_rn(__uint_as_float((bits >> 9) | 0x3f800000u), 1.0f);
}

__device__ inline float xla_log1p(float x) {
  float u  = __fadd_rn(x, 1.0f);
  float lg = (float)log((double)u);
  float sm = __fmul_rn(__fadd_rn(__fmul_rn(-0.5f, x), 1.0f), x);
  return (fabsf(x) < 1e-4f) ? sm : lg;
}

__device__ inline float xla_erfinv(float x) {
  float xx = __fmul_rn(x, x);
  float w  = -xla_log1p(-xx);
  float p;
  if (w < 5.0f) {
    float ww = __fsub_rn(w, 2.5f);
    p = 2.81022636e-08f;
    p = __fadd_rn(3.43273939e-07f,  __fmul_rn(p, ww));
    p = __fadd_rn(-3.5233877e-06f,  __fmul_rn(p, ww));
    p = __fadd_rn(-4.39150654e-06f, __fmul_rn(p, ww));
    p = __fadd_rn(0.00021858087f,   __fmul_rn(p, ww));
    p = __fadd_rn(-0.00125372503f,  __fmul_rn(p, ww));
    p = __fadd_rn(-0.00417768164f,  __fmul_rn(p, ww));
    p = __fadd_rn(0.246640727f,     __fmul_rn(p, ww));
    p = __fadd_rn(1.50140941f,      __fmul_rn(p, ww));
  } else {
    float ww = __fsub_rn(__fsqrt_rn(w), 3.0f);
    p = -0.000200214257f;
    p = __fadd_rn(0.000100950558f,  __fmul_rn(p, ww));
    p = __fadd_rn(0.00134934322f,   __fmul_rn(p, ww));
    p = __fadd_rn(-0.00367342844f,  __fmul_rn(p, ww));
    p = __fadd_rn(0.00573950773f,   __fmul_rn(p, ww));
    p = __fadd_rn(-0.0076224613f,   __fmul_rn(p, ww));
    p = __fadd_rn(0.00943887047f,   __fmul_rn(p, ww));
    p = __fadd_rn(1.00167406f,      __fmul_rn(p, ww));
    p = __fadd_rn(2.83297682f,      __fmul_rn(p, ww));
  }
  return __fmul_rn(p, x);
}

// ---------------- bit-exact chain potential (fallback path) -----------------
// lane owns rows 16m+j (m=0..7); k-ascending FMA chain; partials m-ascending;
// tree = shfl_xor 32,16,8,4 (pairs partial-index bits 3,2,1,0 == SUM_MODE2).
__device__ __attribute__((always_inline)) inline float potential16(
    const float* __restrict__ xr, const float* __restrict__ dr,
    const float* __restrict__ wr, float coef) {
  float z[8] = {0.f, 0.f, 0.f, 0.f, 0.f, 0.f, 0.f, 0.f};
#pragma unroll 2
  for (int q = 0; q < 32; ++q) {
    float4 xv = *(const float4*)(xr + q * 4);
    float4 dv = *(const float4*)(dr + q * 4);
    float c0 = __fadd_rn(xv.x, __fmul_rn(coef, dv.x));
    float c1 = __fadd_rn(xv.y, __fmul_rn(coef, dv.y));
    float c2 = __fadd_rn(xv.z, __fmul_rn(coef, dv.z));
    float c3 = __fadd_rn(xv.w, __fmul_rn(coef, dv.w));
#pragma unroll
    for (int m = 0; m < 8; ++m) {
      float4 wv = *(const float4*)(wr + m * (16 * WS) + q * 4);
      z[m] = __fmaf_rn(c0, wv.x, z[m]);
      z[m] = __fmaf_rn(c1, wv.y, z[m]);
      z[m] = __fmaf_rn(c2, wv.z, z[m]);
      z[m] = __fmaf_rn(c3, wv.w, z[m]);
    }
  }
  float pr = 0.0f;
#pragma unroll
  for (int m = 0; m < 8; ++m) pr = __fadd_rn(pr, __fmul_rn(z[m], z[m]));
#pragma unroll
  for (int msk = 32; msk >= 4; msk >>= 1)
    pr = __fadd_rn(pr, __shfl_xor(pr, msk));
  return __fmul_rn(-0.5f, pr);
}

// certainty margin: >=3x worst-case chain-vs-quadratic rounding discrepancy
__device__ inline double epsb(float u) {
  double au = fabs((double)u);
  return 4e-4 + 8e-5 * au + 8e-6 * au * au;
}

// ---------------- the single fused kernel -----------------------------------
struct KeyArgs {
  uint32_t ky0, ky1;   // k_y
  uint32_t ku0, ku1;   // k_u0
  uint32_t kd0, kd1;   // k_dir
  uint32_t ks[48];     // 24 shrink keys
};

__global__ __launch_bounds__(1024, 1) void slice_fused_kernel(
    const float* __restrict__ X, const float* __restrict__ Wg,
    float* __restrict__ OUT, KeyArgs ka) {
  __shared__ __align__(16) float Wl[128 * WS];  // 67,584 B
  __shared__ __align__(16) float Xl[64 * WS];   // 33,792 B
  __shared__ __align__(16) float Dl[64 * WS];   // 33,792 B

  const int tid   = threadIdx.x;
  const int cbase = blockIdx.x * 64;

  // ---- stage W, X ----
  for (int i = tid; i < 128 * 32; i += 1024) {
    int r = i >> 5, q = i & 31;
    *(float4*)&Wl[r * WS + q * 4] = ((const float4*)Wg)[i];
  }
  for (int i = tid; i < 64 * 32; i += 1024) {
    int c = i >> 5, q = i & 31;
    *(float4*)&Xl[c * WS + q * 4] = ((const float4*)(X + (size_t)(cbase + c) * BD))[q];
  }

  const int wave = tid >> 6, lane = tid & 63;
  const int c    = lane & 3;          // chain-in-wave
  const int j    = lane >> 2;         // partial index 0..15 (rows 16m+j)
  const int cl   = wave * 4 + c;      // chain local (0..63)
  const uint32_t chain = (uint32_t)(cbase + cl);

  // ---- dirs phase (registers only; overlaps staging latency) ----
  {
    const float LO    = __uint_as_float(0xBF7FFFFFu);
    const float SQRT2 = __uint_as_float(0x3FB504F3u);
    float vm[8];
#pragma unroll
    for (int m = 0; m < 8; ++m) {
      uint32_t n = chain * 128u + (uint32_t)(16 * m + j);
      float f  = u01(jbits(ka.kd0, ka.kd1, n));
      float um = fmaxf(LO, __fadd_rn(__fmul_rn(f, 2.0f), LO));
      vm[m] = __fmul_rn(SQRT2, xla_erfinv(um));
    }
    float pr = 0.0f;
#pragma unroll
    for (int m = 0; m < 8; ++m) pr = __fadd_rn(pr, __fmul_rn(vm[m], vm[m]));
#pragma unroll
    for (int msk = 32; msk >= 4; msk >>= 1)
      pr = __fadd_rn(pr, __shfl_xor(pr, msk));
    float nrm = __fsqrt_rn(pr);
#pragma unroll
    for (int m = 0; m < 8; ++m)
      Dl[cl * WS + 16 * m + j] = vm[m] / nrm;
  }

  __syncthreads();  // single block barrier: staging + Dl complete

  const float* xr = &Xl[cl * WS];
  const float* dr = &Dl[cl * WS];
  const float* wr = &Wl[j * WS];      // row 16m+j at wr + m*16*WS

  // ---- fused matvec: za = W x (chain-exact), zb = W d (surrogate only) ----
  float za[8], zb[8];
#pragma unroll
  for (int m = 0; m < 8; ++m) { za[m] = 0.0f; zb[m] = 0.0f; }
#pragma unroll 2
  for (int q = 0; q < 32; ++q) {
    float4 xv = *(const float4*)(xr + q * 4);
    float4 dv = *(const float4*)(dr + q * 4);
#pragma unroll
    for (int m = 0; m < 8; ++m) {
      float4 wv = *(const float4*)(wr + m * (16 * WS) + q * 4);
      za[m] = __fmaf_rn(xv.x, wv.x, za[m]);
      za[m] = __fmaf_rn(xv.y, wv.y, za[m]);
      za[m] = __fmaf_rn(xv.z, wv.z, za[m]);
      za[m] = __fmaf_rn(xv.w, wv.w, za[m]);
      zb[m] = __fmaf_rn(dv.x, wv.x, zb[m]);
      zb[m] = __fmaf_rn(dv.y, wv.y, zb[m]);
      zb[m] = __fmaf_rn(dv.z, wv.z, zb[m]);
      zb[m] = __fmaf_rn(dv.w, wv.w, zb[m]);
    }
  }

  // pot0: chain-exact f32 reduce (partials m-ascending + tree)
  float pr0 = 0.0f;
#pragma unroll
  for (int m = 0; m < 8; ++m) pr0 = __fadd_rn(pr0, __fmul_rn(za[m], za[m]));
#pragma unroll
  for (int msk = 32; msk >= 4; msk >>= 1)
    pr0 = __fadd_rn(pr0, __shfl_xor(pr0, msk));
  float pot0 = __fmul_rn(-0.5f, pr0);

  // g = a·b, h = ‖b‖² in f64 (surrogate only; order-free)
  double gl = 0.0, hl = 0.0;
#pragma unroll
  for (int m = 0; m < 8; ++m) {
    gl += (double)za[m] * (double)zb[m];
    hl += (double)zb[m] * (double)zb[m];
  }
#pragma unroll
  for (int msk = 32; msk >= 4; msk >>= 1) {
    gl += __shfl_xor(gl, msk);
    hl += __shfl_xor(hl, msk);
  }
  const double g = gl, h = hl;
  const double potd0 = (double)pot0;

  // ---- y = log1p(-U) + pot0 (exact f32) ----
  float Uy = u01(jbits(ka.ky0, ka.ky1, chain));
  float y  = __fadd_rn(xla_log1p(-Uy), pot0);
  const double yd = (double)y;
  bool mask0 = (y < pot0);

  // ---- bracket expansion ----
  float lb = 0.0f, ub = 0.0f;
#pragma unroll 1
  for (int side = 0; side < 2; ++side) {
    bool m = mask0;
    float b = 0.0f, pw = 1.0f;
#pragma unroll 1
    for (int i = 0; i < 16; ++i) {
      if (!__any((int)m)) break;
      float step = __fmul_rn(0.1f, pw);
      pw = __fmul_rn(pw, 1.5f);
      if (m) b = side ? __fadd_rn(b, step) : __fsub_rn(b, step);
      double bd   = (double)b;
      double diff = (potd0 - bd * g - 0.5 * bd * bd * h) - yd;
      bool need = m && (fabs(diff) <= epsb(b));
      float pe = 0.0f;
      if (__any((int)need)) pe = potential16(xr, dr, wr, b);
      bool cont = need ? (y < pe) : (diff > 0.0);
      m = m && cont;
    }
    if (side == 0) lb = b; else ub = b;
  }

  // ---- initial proposal ----
  float U0 = u01(jbits(ka.ku0, ka.ku1, chain));
  float u  = __fadd_rn(__fmul_rn(U0, __fsub_rn(ub, lb)), lb);
  bool rej;
  {
    double ud   = (double)u;
    double diff = (potd0 - ud * g - 0.5 * ud * ud * h) - yd;
    bool need = fabs(diff) <= epsb(u);
    float pe = 0.0f;
    if (__any((int)need)) pe = potential16(xr, dr, wr, u);
    rej = need ? (pe < y) : (diff < 0.0);
  }

  // ---- shrinkage ----
#pragma unroll 1
  for (int t = 0; t < 24; ++t) {
    if (!__any((int)rej)) break;
    if (rej) {
      if (u < 0.0f) lb = u; else ub = u;
      float Ut = u01(jbits(ka.ks[2 * t], ka.ks[2 * t + 1], chain));
      u = __fadd_rn(__fmul_rn(Ut, __fsub_rn(ub, lb)), lb);
    }
    double ud   = (double)u;
    double diff = (potd0 - ud * g - 0.5 * ud * ud * h) - yd;
    bool need = rej && (fabs(diff) <= epsb(u));
    float pe = 0.0f;
    if (__any((int)need)) pe = potential16(xr, dr, wr, u);
    bool rj = need ? (pe < y) : (diff < 0.0);
    rej = rej && rj;
  }

  // ---- x_new = x + u*dirs (exact); lane (c,j) writes quads 2j, 2j+1 ----
  float* orow = OUT + (size_t)chain * BD;
#pragma unroll
  for (int hh = 0; hh < 2; ++hh) {
    int q = j * 2 + hh;
    float4 xv = *(const float4*)(xr + q * 4);
    float4 dv = *(const float4*)(dr + q * 4);
    float4 o;
    o.x = __fadd_rn(xv.x, __fmul_rn(u, dv.x));
    o.y = __fadd_rn(xv.y, __fmul_rn(u, dv.y));
    o.z = __fadd_rn(xv.z, __fmul_rn(u, dv.z));
    o.w = __fadd_rn(xv.w, __fmul_rn(u, dv.w));
    *(float4*)&orow[q * 4] = o;
  }
}

// ---------------- launcher ---------------------------------------------------
extern "C" void kernel_launch(void* const* d_in, const int* in_sizes, int n_in,
                              void* d_out, int out_size, void* d_ws, size_t ws_size,
                              hipStream_t stream) {
  (void)in_sizes; (void)n_in; (void)d_ws; (void)ws_size; (void)out_size;
  const float* x = (const float*)d_in[0];
  const float* W = (const float*)d_in[1];
  float* out = (float*)d_out;

  const uint32_t R0 = 0u, R1 = 42u;  // jax.random.key(42)
  uint32_t ky0, ky1, kd0, kd1, ku0, ku1, ksh0, ksh1;
  tf2x32(R0, R1, 0u, 0u, &ky0, &ky1);
  tf2x32(R0, R1, 0u, 1u, &kd0, &kd1);
  tf2x32(R0, R1, 0u, 2u, &ku0, &ku1);
  tf2x32(R0, R1, 0u, 3u, &ksh0, &ksh1);

  KeyArgs ka;
  ka.ky0 = ky0; ka.ky1 = ky1; ka.ku0 = ku0; ka.ku1 = ku1;
  ka.kd0 = kd0; ka.kd1 = kd1;
  for (uint32_t t = 0; t < 24; ++t) {
    uint32_t a, b;
    tf2x32(ksh0, ksh1, 0u, t, &a, &b);
    ka.ks[2 * t] = a; ka.ks[2 * t + 1] = b;
  }

  slice_fused_kernel<<<dim3(NB / 64), dim3(1024), 0, stream>>>(x, W, out, ka);
}

// Round 8
// 138.604 us; speedup vs baseline: 1.2809x; 1.0887x over previous
//
#include <hip/hip_runtime.h>
#include <stdint.h>
#include <math.h>

// ============================================================================
// SliceKernel — exact JAX threefry slice sampler, single fused kernel.
// R8 = R6 + packed-FMA matvec (R7 fixed):
//   - X,D interleaved in LDS as XD[chain][k] = (x_k, d_k) (f32x2, stride 130)
//   - zab[m] = (za[m], zb[m]) via v_pk_fma_f32. VOP3P requires PAIR operands:
//     w comes in as f32x2 pairs w01=(wx,wy), w23=(wz,ww); op_sel broadcasts
//     one half of the pair to both lanes of the result:
//       lo-half wx:  op_sel:[0,0,0] op_sel_hi:[1,0,1]  (src1 -> lo,lo)
//       hi-half wy:  op_sel:[0,1,0] op_sel_hi:[1,1,1]  (src1 -> hi,hi)
//     Per-component IEEE fma == __fmaf_rn => za chain bit-identical.
// VALUE-PATH ARITHMETIC FROZEN (R1-R6, absmax 0.05078125):
//   dirs: u01 -> um -> sqrt2*erfinv -> /nrm; partial j, m-ascending; tree
//         pairing j^8,j^4,j^2,j^1 (shfl_xor 32,16,8,4 with j=lane>>2)
//   pot:  per-row k-ascending FMA chain; partials m-ascending; same tree
//   sampler: b-schedule, u updates, x+u*d exactly as reference
// Decisions: f64 quadratic ps(u)=pot0-u g-u^2 h/2, eps guard, bit-exact
// chain fallback on near-ties (R3-R6: 0 flips).
// ============================================================================

#define BD 128   // feature dim D
#define NB 65536 // chains B
#define WS 132   // padded LDS row stride for W (floats)
#define XDS 130  // XD stride in float2 units

typedef float f32x2 __attribute__((ext_vector_type(2)));

// both halves use src1 pair's LOW register:
#define PK_FMA_LO(acc, xd, wp) \
  asm("v_pk_fma_f32 %0, %1, %2, %0 op_sel_hi:[1,0,1]" \
      : "+v"(acc) : "v"(xd), "v"(wp))
// both halves use src1 pair's HIGH register:
#define PK_FMA_HI(acc, xd, wp) \
  asm("v_pk_fma_f32 %0, %1, %2, %0 op_sel:[0,1,0] op_sel_hi:[1,1,1]" \
      : "+v"(acc) : "v"(xd), "v"(wp))

// ---------------- threefry2x32 (host + device) ------------------------------
__host__ __device__ inline uint32_t rotl32(uint32_t v, int s) {
  return (v << s) | (v >> (32 - s));
}

__host__ __device__ inline void tf2x32(uint32_t k0, uint32_t k1,
                                       uint32_t c0, uint32_t c1,
                                       uint32_t* o0, uint32_t* o1) {
  uint32_t ks2 = k0 ^ k1 ^ 0x1BD11BDAu;
  uint32_t x0 = c0 + k0, x1 = c1 + k1;
#define TFR(r) x0 += x1; x1 = rotl32(x1, (r)); x1 ^= x0;
  TFR(13) TFR(15) TFR(26) TFR(6)
  x0 += k1;  x1 += ks2 + 1u;
  TFR(17) TFR(29) TFR(16) TFR(24)
  x0 += ks2; x1 += k0 + 2u;
  TFR(13) TFR(15) TFR(26) TFR(6)
  x0 += k0;  x1 += k1 + 3u;
  TFR(17) TFR(29) TFR(16) TFR(24)
  x0 += k1;  x1 += ks2 + 4u;
  TFR(13) TFR(15) TFR(26) TFR(6)
  x0 += ks2; x1 += k0 + 5u;
#undef TFR
  *o0 = x0; *o1 = x1;
}

__device__ inline uint32_t jbits(uint32_t k0, uint32_t k1, uint32_t n) {
  uint32_t a, b;
  tf2x32(k0, k1, 0u, n, &a, &b);
  return a ^ b;
}

// ---------------- XLA-exact scalar math -------------------------------------
__device__ inline float u01(uint32_t bits) {
  return __fsub_rn(__uint_as_float((bits >> 9) | 0x3f800000u), 1.0f);
}

__device__ inline float xla_log1p(float x) {
  float u  = __fadd_rn(x, 1.0f);
  float lg = (float)log((double)u);
  float sm = __fmul_rn(__fadd_rn(__fmul_rn(-0.5f, x), 1.0f), x);
  return (fabsf(x) < 1e-4f) ? sm : lg;
}

__device__ inline float xla_erfinv(float x) {
  float xx = __fmul_rn(x, x);
  float w  = -xla_log1p(-xx);
  float p;
  if (w < 5.0f) {
    float ww = __fsub_rn(w, 2.5f);
    p = 2.81022636e-08f;
    p = __fadd_rn(3.43273939e-07f,  __fmul_rn(p, ww));
    p = __fadd_rn(-3.5233877e-06f,  __fmul_rn(p, ww));
    p = __fadd_rn(-4.39150654e-06f, __fmul_rn(p, ww));
    p = __fadd_rn(0.00021858087f,   __fmul_rn(p, ww));
    p = __fadd_rn(-0.00125372503f,  __fmul_rn(p, ww));
    p = __fadd_rn(-0.00417768164f,  __fmul_rn(p, ww));
    p = __fadd_rn(0.246640727f,     __fmul_rn(p, ww));
    p = __fadd_rn(1.50140941f,      __fmul_rn(p, ww));
  } else {
    float ww = __fsub_rn(__fsqrt_rn(w), 3.0f);
    p = -0.000200214257f;
    p = __fadd_rn(0.000100950558f,  __fmul_rn(p, ww));
    p = __fadd_rn(0.00134934322f,   __fmul_rn(p, ww));
    p = __fadd_rn(-0.00367342844f,  __fmul_rn(p, ww));
    p = __fadd_rn(0.00573950773f,   __fmul_rn(p, ww));
    p = __fadd_rn(-0.0076224613f,   __fmul_rn(p, ww));
    p = __fadd_rn(0.00943887047f,   __fmul_rn(p, ww));
    p = __fadd_rn(1.00167406f,      __fmul_rn(p, ww));
    p = __fadd_rn(2.83297682f,      __fmul_rn(p, ww));
  }
  return __fmul_rn(p, x);
}

// ---------------- bit-exact chain potential (fallback path) -----------------
__device__ __attribute__((always_inline)) inline float potential16(
    const f32x2* __restrict__ xdr, const float* __restrict__ wr, float coef) {
  float z[8] = {0.f, 0.f, 0.f, 0.f, 0.f, 0.f, 0.f, 0.f};
#pragma unroll 2
  for (int q = 0; q < 32; ++q) {
    float4 p01 = *(const float4*)(xdr + q * 4);
    float4 p23 = *(const float4*)(xdr + q * 4 + 2);
    float c0 = __fadd_rn(p01.x, __fmul_rn(coef, p01.y));
    float c1 = __fadd_rn(p01.z, __fmul_rn(coef, p01.w));
    float c2 = __fadd_rn(p23.x, __fmul_rn(coef, p23.y));
    float c3 = __fadd_rn(p23.z, __fmul_rn(coef, p23.w));
#pragma unroll
    for (int m = 0; m < 8; ++m) {
      float4 wv = *(const float4*)(wr + m * (16 * WS) + q * 4);
      z[m] = __fmaf_rn(c0, wv.x, z[m]);
      z[m] = __fmaf_rn(c1, wv.y, z[m]);
      z[m] = __fmaf_rn(c2, wv.z, z[m]);
      z[m] = __fmaf_rn(c3, wv.w, z[m]);
    }
  }
  float pr = 0.0f;
#pragma unroll
  for (int m = 0; m < 8; ++m) pr = __fadd_rn(pr, __fmul_rn(z[m], z[m]));
#pragma unroll
  for (int msk = 32; msk >= 4; msk >>= 1)
    pr = __fadd_rn(pr, __shfl_xor(pr, msk));
  return __fmul_rn(-0.5f, pr);
}

// certainty margin: >=3x worst-case chain-vs-quadratic rounding discrepancy
__device__ inline double epsb(float u) {
  double au = fabs((double)u);
  return 4e-4 + 8e-5 * au + 8e-6 * au * au;
}

// ---------------- the single fused kernel -----------------------------------
struct KeyArgs {
  uint32_t ky0, ky1;   // k_y
  uint32_t ku0, ku1;   // k_u0
  uint32_t kd0, kd1;   // k_dir
  uint32_t ks[48];     // 24 shrink keys
};

__global__ __launch_bounds__(1024, 1) void slice_fused_kernel(
    const float* __restrict__ X, const float* __restrict__ Wg,
    float* __restrict__ OUT, KeyArgs ka) {
  __shared__ __align__(16) float Wl[128 * WS];    // 67,584 B
  __shared__ __align__(16) f32x2 XDl[64 * XDS];   // 66,560 B (total 134,144)

  const int tid   = threadIdx.x;
  const int cbase = blockIdx.x * 64;

  // ---- stage W (padded rows) ----
  for (int i = tid; i < 128 * 32; i += 1024) {
    int r = i >> 5, q = i & 31;
    *(float4*)&Wl[r * WS + q * 4] = ((const float4*)Wg)[i];
  }
  // ---- stage X into .x slots of XD ----
  for (int i = tid; i < 64 * 32; i += 1024) {
    int cc = i >> 5, q = i & 31;
    float4 xv = ((const float4*)(X + (size_t)(cbase + cc) * BD))[q];
    float* b0 = (float*)&XDl[cc * XDS + q * 4];
    b0[0] = xv.x; b0[2] = xv.y; b0[4] = xv.z; b0[6] = xv.w;
  }

  const int wave = tid >> 6, lane = tid & 63;
  const int c    = lane & 3;          // chain-in-wave
  const int j    = lane >> 2;         // partial index 0..15 (rows 16m+j)
  const int cl   = wave * 4 + c;      // chain local (0..63)
  const uint32_t chain = (uint32_t)(cbase + cl);

  // ---- dirs phase (registers; writes .y slots of XD) ----
  {
    const float LO    = __uint_as_float(0xBF7FFFFFu);
    const float SQRT2 = __uint_as_float(0x3FB504F3u);
    float vm[8];
#pragma unroll
    for (int m = 0; m < 8; ++m) {
      uint32_t n = chain * 128u + (uint32_t)(16 * m + j);
      float f  = u01(jbits(ka.kd0, ka.kd1, n));
      float um = fmaxf(LO, __fadd_rn(__fmul_rn(f, 2.0f), LO));
      vm[m] = __fmul_rn(SQRT2, xla_erfinv(um));
    }
    float pr = 0.0f;
#pragma unroll
    for (int m = 0; m < 8; ++m) pr = __fadd_rn(pr, __fmul_rn(vm[m], vm[m]));
#pragma unroll
    for (int msk = 32; msk >= 4; msk >>= 1)
      pr = __fadd_rn(pr, __shfl_xor(pr, msk));
    float nrm = __fsqrt_rn(pr);
#pragma unroll
    for (int m = 0; m < 8; ++m)
      ((float*)&XDl[cl * XDS + 16 * m + j])[1] = vm[m] / nrm;
  }

  __syncthreads();  // single block barrier: staging + dirs complete

  const f32x2* xdr = &XDl[cl * XDS];
  const float* wr  = &Wl[j * WS];     // row 16m+j at wr + m*16*WS

  // ---- packed fused matvec: zab[m] = (za[m], zb[m]) ----
  // lo: za += x_k*w (chain-exact); hi: zb += d_k*w (surrogate only)
  f32x2 zab[8];
#pragma unroll
  for (int m = 0; m < 8; ++m) zab[m] = (f32x2){0.0f, 0.0f};
#pragma unroll 2
  for (int q = 0; q < 32; ++q) {
    float4 p01 = *(const float4*)(xdr + q * 4);
    float4 p23 = *(const float4*)(xdr + q * 4 + 2);
    f32x2 xd0 = {p01.x, p01.y}, xd1 = {p01.z, p01.w};
    f32x2 xd2 = {p23.x, p23.y}, xd3 = {p23.z, p23.w};
#pragma unroll
    for (int m = 0; m < 8; ++m) {
      const float* wb = wr + m * (16 * WS) + q * 4;
      f32x2 w01 = *(const f32x2*)(wb);      // (wx, wy) pair
      f32x2 w23 = *(const f32x2*)(wb + 2);  // (wz, ww) pair
      PK_FMA_LO(zab[m], xd0, w01);          // both halves * wx
      PK_FMA_HI(zab[m], xd1, w01);          // both halves * wy
      PK_FMA_LO(zab[m], xd2, w23);          // both halves * wz
      PK_FMA_HI(zab[m], xd3, w23);          // both halves * ww
    }
  }

  // pot0: chain-exact f32 reduce (partials m-ascending + tree)
  float pr0 = 0.0f;
#pragma unroll
  for (int m = 0; m < 8; ++m) pr0 = __fadd_rn(pr0, __fmul_rn(zab[m].x, zab[m].x));
#pragma unroll
  for (int msk = 32; msk >= 4; msk >>= 1)
    pr0 = __fadd_rn(pr0, __shfl_xor(pr0, msk));
  float pot0 = __fmul_rn(-0.5f, pr0);

  // g = a·b, h = ‖b‖² in f64 (surrogate only; order-free)
  double gl = 0.0, hl = 0.0;
#pragma unroll
  for (int m = 0; m < 8; ++m) {
    gl += (double)zab[m].x * (double)zab[m].y;
    hl += (double)zab[m].y * (double)zab[m].y;
  }
#pragma unroll
  for (int msk = 32; msk >= 4; msk >>= 1) {
    gl += __shfl_xor(gl, msk);
    hl += __shfl_xor(hl, msk);
  }
  const double g = gl, h = hl;
  const double potd0 = (double)pot0;

  // ---- y = log1p(-U) + pot0 (exact f32) ----
  float Uy = u01(jbits(ka.ky0, ka.ky1, chain));
  float y  = __fadd_rn(xla_log1p(-Uy), pot0);
  const double yd = (double)y;
  bool mask0 = (y < pot0);

  // ---- bracket expansion ----
  float lb = 0.0f, ub = 0.0f;
#pragma unroll 1
  for (int side = 0; side < 2; ++side) {
    bool m = mask0;
    float b = 0.0f, pw = 1.0f;
#pragma unroll 1
    for (int i = 0; i < 16; ++i) {
      if (!__any((int)m)) break;
      float step = __fmul_rn(0.1f, pw);
      pw = __fmul_rn(pw, 1.5f);
      if (m) b = side ? __fadd_rn(b, step) : __fsub_rn(b, step);
      double bd   = (double)b;
      double diff = (potd0 - bd * g - 0.5 * bd * bd * h) - yd;
      bool need = m && (fabs(diff) <= epsb(b));
      float pe = 0.0f;
      if (__any((int)need)) pe = potential16(xdr, wr, b);
      bool cont = need ? (y < pe) : (diff > 0.0);
      m = m && cont;
    }
    if (side == 0) lb = b; else ub = b;
  }

  // ---- initial proposal ----
  float U0 = u01(jbits(ka.ku0, ka.ku1, chain));
  float u  = __fadd_rn(__fmul_rn(U0, __fsub_rn(ub, lb)), lb);
  bool rej;
  {
    double ud   = (double)u;
    double diff = (potd0 - ud * g - 0.5 * ud * ud * h) - yd;
    bool need = fabs(diff) <= epsb(u);
    float pe = 0.0f;
    if (__any((int)need)) pe = potential16(xdr, wr, u);
    rej = need ? (pe < y) : (diff < 0.0);
  }

  // ---- shrinkage ----
#pragma unroll 1
  for (int t = 0; t < 24; ++t) {
    if (!__any((int)rej)) break;
    if (rej) {
      if (u < 0.0f) lb = u; else ub = u;
      float Ut = u01(jbits(ka.ks[2 * t], ka.ks[2 * t + 1], chain));
      u = __fadd_rn(__fmul_rn(Ut, __fsub_rn(ub, lb)), lb);
    }
    double ud   = (double)u;
    double diff = (potd0 - ud * g - 0.5 * ud * ud * h) - yd;
    bool need = rej && (fabs(diff) <= epsb(u));
    float pe = 0.0f;
    if (__any((int)need)) pe = potential16(xdr, wr, u);
    bool rj = need ? (pe < y) : (diff < 0.0);
    rej = rej && rj;
  }

  // ---- x_new = x + u*dirs (exact); lane (c,j) writes quads 2j, 2j+1 ----
  float* orow = OUT + (size_t)chain * BD;
#pragma unroll
  for (int hh = 0; hh < 2; ++hh) {
    int q2 = j * 2 + hh;
    float4 p01 = *(const float4*)(xdr + q2 * 4);
    float4 p23 = *(const float4*)(xdr + q2 * 4 + 2);
    float4 o;
    o.x = __fadd_rn(p01.x, __fmul_rn(u, p01.y));
    o.y = __fadd_rn(p01.z, __fmul_rn(u, p01.w));
    o.z = __fadd_rn(p23.x, __fmul_rn(u, p23.y));
    o.w = __fadd_rn(p23.z, __fmul_rn(u, p23.w));
    *(float4*)&orow[q2 * 4] = o;
  }
}

// ---------------- launcher ---------------------------------------------------
extern "C" void kernel_launch(void* const* d_in, const int* in_sizes, int n_in,
                              void* d_out, int out_size, void* d_ws, size_t ws_size,
                              hipStream_t stream) {
  (void)in_sizes; (void)n_in; (void)d_ws; (void)ws_size; (void)out_size;
  const float* x = (const float*)d_in[0];
  const float* W = (const float*)d_in[1];
  float* out = (float*)d_out;

  const uint32_t R0 = 0u, R1 = 42u;  // jax.random.key(42)
  uint32_t ky0, ky1, kd0, kd1, ku0, ku1, ksh0, ksh1;
  tf2x32(R0, R1, 0u, 0u, &ky0, &ky1);
  tf2x32(R0, R1, 0u, 1u, &kd0, &kd1);
  tf2x32(R0, R1, 0u, 2u, &ku0, &ku1);
  tf2x32(R0, R1, 0u, 3u, &ksh0, &ksh1);

  KeyArgs ka;
  ka.ky0 = ky0; ka.ky1 = ky1; ka.ku0 = ku0; ka.ku1 = ku1;
  ka.kd0 = kd0; ka.kd1 = kd1;
  for (uint32_t t = 0; t < 24; ++t) {
    uint32_t a, b;
    tf2x32(ksh0, ksh1, 0u, t, &a, &b);
    ka.ks[2 * t] = a; ka.ks[2 * t + 1] = b;
  }

  slice_fused_kernel<<<dim3(NB / 64), dim3(1024), 0, stream>>>(x, W, out, ka);
}